// Round 8
// baseline (207.970 us; speedup 1.0000x reference)
//
#include <hip/hip_runtime.h>
#include <hip/hip_bf16.h>

#define N 8192
#define D 768
#define TEMP_INV 20.0f
#define NTILES 2080   // 64x64 tile-grid upper triangle incl. diagonal

typedef __attribute__((ext_vector_type(4))) float f32x4;
typedef __attribute__((ext_vector_type(4))) int i32x4;
typedef __attribute__((ext_vector_type(8))) int i32x8;

#define SCALE1 0x7F7F7F7F  // e8m0 = 127 in all 4 bytes -> scale 1.0

// Workspace layout (floats):
//   [0,   N)     rowsum   (zeroed by norm_kernel)
//   [N,  2N)     pos      (fully written by sim_kernel diag tiles)
//   [2N, 2N+16)  pad
//   [2N+16, ...) xn fp8-e4m3 [N][768] bytes

// ---------------------------------------------------------------------------
// Kernel 1: row L2-normalize fp32 -> fp8 e4m3. One row per wave (4 rows/block).
// Also zeroes out[0] (kernel-completion release makes it visible to
// loss_kernel's device-scope atomicAdd; saves the hipMemsetAsync dispatch).
__global__ __launch_bounds__(256) void norm_kernel(
    const float* __restrict__ x, unsigned char* __restrict__ xn,
    float* __restrict__ rowsum, float* __restrict__ out) {
  int t = threadIdx.x, w = t >> 6, lane = t & 63;
  int row = blockIdx.x * 4 + w;
  const float4* xr = (const float4*)(x + (size_t)row * D);
  float4 v[3];
  v[0] = xr[lane];
  v[1] = xr[lane + 64];
  v[2] = xr[lane + 128];
  float ss = 0.0f;
#pragma unroll
  for (int i = 0; i < 3; ++i)
    ss += v[i].x * v[i].x + v[i].y * v[i].y + v[i].z * v[i].z + v[i].w * v[i].w;
#pragma unroll
  for (int m = 32; m; m >>= 1) ss += __shfl_xor(ss, m);
  float inv = 1.0f / fmaxf(sqrtf(ss), 1e-8f);
  unsigned int* xo = (unsigned int*)(xn + (size_t)row * D);
#pragma unroll
  for (int i = 0; i < 3; ++i) {
    int p = __builtin_amdgcn_cvt_pk_fp8_f32(v[i].x * inv, v[i].y * inv, 0, false);
    p = __builtin_amdgcn_cvt_pk_fp8_f32(v[i].z * inv, v[i].w * inv, p, true);
    xo[lane + 64 * i] = p;
  }
  if (t < 4) rowsum[blockIdx.x * 4 + t] = 0.0f;
  if (blockIdx.x == 0 && t == 0) out[0] = 0.0f;
}

// ---------------------------------------------------------------------------
// Kernel 2: upper-triangle 128x128 tiles of S = Xn * Xn^T via MX-scaled fp8
// MFMA (K=128, scales=1.0 -> plain fp8 GEMM at 2x non-scaled rate).
// Round-0 body (session best; 4 schedule restructures all regressed).
// __launch_bounds__(256,5): 5 blocks x 32 KB = 160 KiB LDS exactly ->
// 20 waves/CU (+25% TLP vs r0's 4 blocks) to fill the barrier-drain stalls
// that source-level pipelining could not remove (m114 wave-overlap is the
// one mechanism that works in this structure).
__global__ __launch_bounds__(256, 5) void sim_kernel(
    const unsigned char* __restrict__ xn, float* __restrict__ rowsum,
    float* __restrict__ pos) {
  // ---- tile decode: blockIdx -> XCD-chunk position -> supertile -> (bi,bj)
  static const short stbase[37] = {
      0, 36, 100, 164, 228, 292, 356, 420,
      484, 520, 584, 648, 712, 776, 840,
      904, 940, 1004, 1068, 1132, 1196,
      1260, 1296, 1360, 1424, 1488,
      1552, 1588, 1652, 1716,
      1780, 1816, 1880,
      1944, 1980,
      2044, 2080};
  static const char sti[36] = {0,0,0,0,0,0,0,0, 1,1,1,1,1,1,1, 2,2,2,2,2,2,
                               3,3,3,3,3, 4,4,4,4, 5,5,5, 6,6, 7};
  static const char stj[36] = {0,1,2,3,4,5,6,7, 1,2,3,4,5,6,7, 2,3,4,5,6,7,
                               3,4,5,6,7, 4,5,6,7, 5,6,7, 6,7, 7};
  int b = blockIdx.x;
  int p = 260 * (b & 7) + (b >> 3);
  int s = 0;
  while ((int)stbase[s + 1] <= p) ++s;
  int wofs = p - stbase[s];
  int SI = sti[s], SJ = stj[s];
  int bi, bj;
  if (SI == SJ) {  // diagonal supertile: triangular 8x8, counts 8,7,...,1
    int di = 0, cum = 0;
    while (wofs >= cum + (8 - di)) { cum += 8 - di; ++di; }
    bi = SI * 8 + di;
    bj = SI * 8 + di + (wofs - cum);
  } else {
    bi = SI * 8 + (wofs >> 3);
    bj = SJ * 8 + (wofs & 7);
  }

  __shared__ i32x4 As4[128 * 8];  // 128 rows x 8 16B-units = 16 KB
  __shared__ i32x4 Bs4[128 * 8];

  int t = threadIdx.x;
  int w = t >> 6, lane = t & 63;
  int q = lane >> 4, cl = lane & 15;
  int wm = w >> 1, wn = w & 1;

  f32x4 acc[4][4] = {};

  // staging: thread t fills physical unit (t&7) of row (t>>3)+32*rr; source
  // logical unit = (t&7) ^ (row&7); row&7 == (t>>3)&7 for all rr (32%8==0)
  int ulog = (((t & 7) ^ ((t >> 3) & 7))) * 16;
  const unsigned char* Ab = xn + (size_t)(bi * 128 + (t >> 3)) * D + ulog;
  const unsigned char* Bb = xn + (size_t)(bj * 128 + (t >> 3)) * D + ulog;

  // fragment reads: lane needs logical units 2q, 2q+1 of its row;
  // physical = logical ^ (row&7), row&7 == cl&7 (64,16 are 0 mod 8)
  int u0 = (2 * q) ^ (cl & 7);
  int u1 = u0 ^ 1;

  for (int kc = 0; kc < 6; ++kc) {
    int k0 = kc * 128;
#pragma unroll
    for (int rr = 0; rr < 4; ++rr) {
      __builtin_amdgcn_global_load_lds(
          (const __attribute__((address_space(1))) unsigned int*)(Ab + (size_t)(rr * 32) * D + k0),
          (__attribute__((address_space(3))) unsigned int*)(As4 + rr * 256 + t), 16, 0, 0);
      __builtin_amdgcn_global_load_lds(
          (const __attribute__((address_space(1))) unsigned int*)(Bb + (size_t)(rr * 32) * D + k0),
          (__attribute__((address_space(3))) unsigned int*)(Bs4 + rr * 256 + t), 16, 0, 0);
    }
    __syncthreads();

    union Frag { i32x8 v8; struct { i32x4 lo, hi; } pr; };
    Frag a[4], bb[4];
#pragma unroll
    for (int m = 0; m < 4; ++m) {
      int rowb = (wm * 64 + m * 16 + cl) * 8;
      a[m].pr.lo = As4[rowb + u0];
      a[m].pr.hi = As4[rowb + u1];
    }
#pragma unroll
    for (int n = 0; n < 4; ++n) {
      int rowb = (wn * 64 + n * 16 + cl) * 8;
      bb[n].pr.lo = Bs4[rowb + u0];
      bb[n].pr.hi = Bs4[rowb + u1];
    }
#pragma unroll
    for (int m = 0; m < 4; ++m)
#pragma unroll
      for (int n = 0; n < 4; ++n)
        acc[m][n] = __builtin_amdgcn_mfma_scale_f32_16x16x128_f8f6f4(
            a[m].v8, bb[n].v8, acc[m][n], 0, 0, 0, SCALE1, 0, SCALE1);
    __syncthreads();
  }

  // Epilogue. C/D layout: col = lane&15, row = (lane>>4)*4 + reg (shape-det.).
  int gi0 = bi * 128 + wm * 64;
  int gj0 = bj * 128 + wn * 64;

  float rowp[4][4] = {};
  float colp[4] = {};

  if (bi == bj) {
#pragma unroll
    for (int m = 0; m < 4; ++m)
#pragma unroll
      for (int n = 0; n < 4; ++n)
#pragma unroll
        for (int r = 0; r < 4; ++r) {
          float sv = acc[m][n][r];
          int row = gi0 + m * 16 + q * 4 + r;
          int col = gj0 + n * 16 + cl;
          float e = __expf(TEMP_INV * sv - 20.0f);
          if (col == row) e = 0.0f;
          if (col == (row ^ 1)) pos[row] = TEMP_INV * sv;
          rowp[m][r] += e;
        }
  } else {
#pragma unroll
    for (int m = 0; m < 4; ++m)
#pragma unroll
      for (int n = 0; n < 4; ++n)
#pragma unroll
        for (int r = 0; r < 4; ++r) {
          float e = __expf(TEMP_INV * acc[m][n][r] - 20.0f);
          rowp[m][r] += e;
          colp[n] += e;
        }
  }

#pragma unroll
  for (int m = 0; m < 4; ++m)
#pragma unroll
    for (int r = 0; r < 4; ++r) {
      float v = rowp[m][r];
      v += __shfl_xor(v, 1);
      v += __shfl_xor(v, 2);
      v += __shfl_xor(v, 4);
      v += __shfl_xor(v, 8);
      if (cl == 0) atomicAdd(&rowsum[gi0 + m * 16 + q * 4 + r], v);
    }
  if (bi != bj) {
#pragma unroll
    for (int n = 0; n < 4; ++n) {
      float v = colp[n];
      v += __shfl_xor(v, 16);
      v += __shfl_xor(v, 32);
      if (q == 0) atomicAdd(&rowsum[gj0 + n * 16 + cl], v);
    }
  }
}

// ---------------------------------------------------------------------------
// Kernel 3: loss = mean_i (20 + log(rowsum[i]) - pos[i]).
// 32 blocks x 256 threads, one row/thread, block-partial atomicAdd into out
// (zeroed by norm_kernel).
__global__ __launch_bounds__(256) void loss_kernel(
    const float* __restrict__ rowsum, const float* __restrict__ pos,
    float* __restrict__ out) {
  int t = threadIdx.x;
  int i = blockIdx.x * 256 + t;
  float acc = 20.0f + __logf(rowsum[i]) - pos[i];
#pragma unroll
  for (int m = 32; m; m >>= 1) acc += __shfl_xor(acc, m);
  __shared__ float wsum[4];
  if ((t & 63) == 0) wsum[t >> 6] = acc;
  __syncthreads();
  if (t == 0) {
    float tot = wsum[0] + wsum[1] + wsum[2] + wsum[3];
    atomicAdd(out, tot * (1.0f / (float)N));
  }
}

extern "C" void kernel_launch(void* const* d_in, const int* in_sizes, int n_in,
                              void* d_out, int out_size, void* d_ws, size_t ws_size,
                              hipStream_t stream) {
  const float* x = (const float*)d_in[0];
  float* rowsum = (float*)d_ws;
  float* pos = rowsum + N;
  unsigned char* xn = (unsigned char*)(rowsum + 2 * N + 16);

  norm_kernel<<<N / 4, 256, 0, stream>>>(x, xn, rowsum, (float*)d_out);
  sim_kernel<<<NTILES, 256, 0, stream>>>(xn, rowsum, pos);
  loss_kernel<<<N / 256, 256, 0, stream>>>(rowsum, pos, (float*)d_out);
}

// Round 9
// 125.560 us; speedup vs baseline: 1.6563x; 1.6563x over previous
//
#include <hip/hip_runtime.h>
#include <hip/hip_bf16.h>

#define N 8192
#define D 768
#define TEMP_INV 20.0f
#define NTILES 2080   // 64x64 tile-grid upper triangle incl. diagonal

typedef __attribute__((ext_vector_type(4))) float f32x4;
typedef __attribute__((ext_vector_type(4))) int i32x4;
typedef __attribute__((ext_vector_type(8))) int i32x8;

#define SCALE1 0x7F7F7F7F  // e8m0 = 127 in all 4 bytes -> scale 1.0

// Workspace layout (floats):
//   [0,   N)     rowsum   (zeroed by norm_kernel)
//   [N,  2N)     pos      (fully written by sim_kernel diag tiles)
//   [2N, 2N+16)  pad
//   [2N+16, ...) xn fp8-e4m3 [N][768] bytes

// ---------------------------------------------------------------------------
// Kernel 1: row L2-normalize fp32 -> fp8 e4m3. One row per wave (4 rows/block).
// Also zeroes out[0] (kernel-completion release -> visible to loss_kernel's
// device-scope atomicAdd; saves a hipMemsetAsync dispatch, ~5us/dispatch).
__global__ __launch_bounds__(256) void norm_kernel(
    const float* __restrict__ x, unsigned char* __restrict__ xn,
    float* __restrict__ rowsum, float* __restrict__ out) {
  int t = threadIdx.x, w = t >> 6, lane = t & 63;
  int row = blockIdx.x * 4 + w;
  const float4* xr = (const float4*)(x + (size_t)row * D);
  float4 v[3];
  v[0] = xr[lane];
  v[1] = xr[lane + 64];
  v[2] = xr[lane + 128];
  float ss = 0.0f;
#pragma unroll
  for (int i = 0; i < 3; ++i)
    ss += v[i].x * v[i].x + v[i].y * v[i].y + v[i].z * v[i].z + v[i].w * v[i].w;
#pragma unroll
  for (int m = 32; m; m >>= 1) ss += __shfl_xor(ss, m);
  float inv = 1.0f / fmaxf(sqrtf(ss), 1e-8f);
  unsigned int* xo = (unsigned int*)(xn + (size_t)row * D);
#pragma unroll
  for (int i = 0; i < 3; ++i) {
    int p = __builtin_amdgcn_cvt_pk_fp8_f32(v[i].x * inv, v[i].y * inv, 0, false);
    p = __builtin_amdgcn_cvt_pk_fp8_f32(v[i].z * inv, v[i].w * inv, p, true);
    xo[lane + 64 * i] = p;
  }
  if (t < 4) rowsum[blockIdx.x * 4 + t] = 0.0f;
  if (blockIdx.x == 0 && t == 0) out[0] = 0.0f;
}

// ---------------------------------------------------------------------------
// Kernel 2: upper-triangle 128x128 tiles of S = Xn * Xn^T via MX-scaled fp8
// MFMA (K=128, scales=1.0 -> plain fp8 GEMM at 2x non-scaled rate).
//
// Round-0 body at __launch_bounds__(256,4) -- the session's empirical fixed
// point (59.7-62.4us). Do NOT raise the occupancy floor: (256,5) forces
// VGPR 48 < the 64 live acc regs -> accumulator spill to scratch (375 GB
// HBM writes, 2.4x slowdown, round 8). Schedule restructures (dbuf, 3-phase,
// m201 4-phase counted-vmcnt, 512-thread) all regressed (rounds 1-4);
// in-kernel cross-XCD sync costs ~80us (rounds 5-6).
__global__ __launch_bounds__(256, 4) void sim_kernel(
    const unsigned char* __restrict__ xn, float* __restrict__ rowsum,
    float* __restrict__ pos) {
  // ---- tile decode: blockIdx -> XCD-chunk position -> supertile -> (bi,bj)
  static const short stbase[37] = {
      0, 36, 100, 164, 228, 292, 356, 420,
      484, 520, 584, 648, 712, 776, 840,
      904, 940, 1004, 1068, 1132, 1196,
      1260, 1296, 1360, 1424, 1488,
      1552, 1588, 1652, 1716,
      1780, 1816, 1880,
      1944, 1980,
      2044, 2080};
  static const char sti[36] = {0,0,0,0,0,0,0,0, 1,1,1,1,1,1,1, 2,2,2,2,2,2,
                               3,3,3,3,3, 4,4,4,4, 5,5,5, 6,6, 7};
  static const char stj[36] = {0,1,2,3,4,5,6,7, 1,2,3,4,5,6,7, 2,3,4,5,6,7,
                               3,4,5,6,7, 4,5,6,7, 5,6,7, 6,7, 7};
  int b = blockIdx.x;
  int p = 260 * (b & 7) + (b >> 3);
  int s = 0;
  while ((int)stbase[s + 1] <= p) ++s;
  int wofs = p - stbase[s];
  int SI = sti[s], SJ = stj[s];
  int bi, bj;
  if (SI == SJ) {  // diagonal supertile: triangular 8x8, counts 8,7,...,1
    int di = 0, cum = 0;
    while (wofs >= cum + (8 - di)) { cum += 8 - di; ++di; }
    bi = SI * 8 + di;
    bj = SI * 8 + di + (wofs - cum);
  } else {
    bi = SI * 8 + (wofs >> 3);
    bj = SJ * 8 + (wofs & 7);
  }

  __shared__ i32x4 As4[128 * 8];  // 128 rows x 8 16B-units = 16 KB
  __shared__ i32x4 Bs4[128 * 8];

  int t = threadIdx.x;
  int w = t >> 6, lane = t & 63;
  int q = lane >> 4, cl = lane & 15;
  int wm = w >> 1, wn = w & 1;

  f32x4 acc[4][4] = {};

  // staging: thread t fills physical unit (t&7) of row (t>>3)+32*rr; source
  // logical unit = (t&7) ^ (row&7); row&7 == (t>>3)&7 for all rr (32%8==0)
  int ulog = (((t & 7) ^ ((t >> 3) & 7))) * 16;
  const unsigned char* Ab = xn + (size_t)(bi * 128 + (t >> 3)) * D + ulog;
  const unsigned char* Bb = xn + (size_t)(bj * 128 + (t >> 3)) * D + ulog;

  // fragment reads: lane needs logical units 2q, 2q+1 of its row;
  // physical = logical ^ (row&7), row&7 == cl&7 (64,16 are 0 mod 8)
  int u0 = (2 * q) ^ (cl & 7);
  int u1 = u0 ^ 1;

  for (int kc = 0; kc < 6; ++kc) {
    int k0 = kc * 128;
#pragma unroll
    for (int rr = 0; rr < 4; ++rr) {
      __builtin_amdgcn_global_load_lds(
          (const __attribute__((address_space(1))) unsigned int*)(Ab + (size_t)(rr * 32) * D + k0),
          (__attribute__((address_space(3))) unsigned int*)(As4 + rr * 256 + t), 16, 0, 0);
      __builtin_amdgcn_global_load_lds(
          (const __attribute__((address_space(1))) unsigned int*)(Bb + (size_t)(rr * 32) * D + k0),
          (__attribute__((address_space(3))) unsigned int*)(Bs4 + rr * 256 + t), 16, 0, 0);
    }
    __syncthreads();

    union Frag { i32x8 v8; struct { i32x4 lo, hi; } pr; };
    Frag a[4], bb[4];
#pragma unroll
    for (int m = 0; m < 4; ++m) {
      int rowb = (wm * 64 + m * 16 + cl) * 8;
      a[m].pr.lo = As4[rowb + u0];
      a[m].pr.hi = As4[rowb + u1];
    }
#pragma unroll
    for (int n = 0; n < 4; ++n) {
      int rowb = (wn * 64 + n * 16 + cl) * 8;
      bb[n].pr.lo = Bs4[rowb + u0];
      bb[n].pr.hi = Bs4[rowb + u1];
    }
#pragma unroll
    for (int m = 0; m < 4; ++m)
#pragma unroll
      for (int n = 0; n < 4; ++n)
        acc[m][n] = __builtin_amdgcn_mfma_scale_f32_16x16x128_f8f6f4(
            a[m].v8, bb[n].v8, acc[m][n], 0, 0, 0, SCALE1, 0, SCALE1);
    __syncthreads();
  }

  // Epilogue. C/D layout: col = lane&15, row = (lane>>4)*4 + reg (shape-det.).
  int gi0 = bi * 128 + wm * 64;
  int gj0 = bj * 128 + wn * 64;

  float rowp[4][4] = {};
  float colp[4] = {};

  if (bi == bj) {
#pragma unroll
    for (int m = 0; m < 4; ++m)
#pragma unroll
      for (int n = 0; n < 4; ++n)
#pragma unroll
        for (int r = 0; r < 4; ++r) {
          float sv = acc[m][n][r];
          int row = gi0 + m * 16 + q * 4 + r;
          int col = gj0 + n * 16 + cl;
          float e = __expf(TEMP_INV * sv - 20.0f);
          if (col == row) e = 0.0f;
          if (col == (row ^ 1)) pos[row] = TEMP_INV * sv;
          rowp[m][r] += e;
        }
  } else {
#pragma unroll
    for (int m = 0; m < 4; ++m)
#pragma unroll
      for (int n = 0; n < 4; ++n)
#pragma unroll
        for (int r = 0; r < 4; ++r) {
          float e = __expf(TEMP_INV * acc[m][n][r] - 20.0f);
          rowp[m][r] += e;
          colp[n] += e;
        }
  }

#pragma unroll
  for (int m = 0; m < 4; ++m)
#pragma unroll
    for (int r = 0; r < 4; ++r) {
      float v = rowp[m][r];
      v += __shfl_xor(v, 1);
      v += __shfl_xor(v, 2);
      v += __shfl_xor(v, 4);
      v += __shfl_xor(v, 8);
      if (cl == 0) atomicAdd(&rowsum[gi0 + m * 16 + q * 4 + r], v);
    }
  if (bi != bj) {
#pragma unroll
    for (int n = 0; n < 4; ++n) {
      float v = colp[n];
      v += __shfl_xor(v, 16);
      v += __shfl_xor(v, 32);
      if (q == 0) atomicAdd(&rowsum[gj0 + n * 16 + cl], v);
    }
  }
}

// ---------------------------------------------------------------------------
// Kernel 3: loss = mean_i (20 + log(rowsum[i]) - pos[i]).
// 32 blocks x 256 threads, one row/thread, block-partial atomicAdd into out
// (zeroed by norm_kernel -- no memset dispatch needed).
__global__ __launch_bounds__(256) void loss_kernel(
    const float* __restrict__ rowsum, const float* __restrict__ pos,
    float* __restrict__ out) {
  int t = threadIdx.x;
  int i = blockIdx.x * 256 + t;
  float acc = 20.0f + __logf(rowsum[i]) - pos[i];
#pragma unroll
  for (int m = 32; m; m >>= 1) acc += __shfl_xor(acc, m);
  __shared__ float wsum[4];
  if ((t & 63) == 0) wsum[t >> 6] = acc;
  __syncthreads();
  if (t == 0) {
    float tot = wsum[0] + wsum[1] + wsum[2] + wsum[3];
    atomicAdd(out, tot * (1.0f / (float)N));
  }
}

extern "C" void kernel_launch(void* const* d_in, const int* in_sizes, int n_in,
                              void* d_out, int out_size, void* d_ws, size_t ws_size,
                              hipStream_t stream) {
  const float* x = (const float*)d_in[0];
  float* rowsum = (float*)d_ws;
  float* pos = rowsum + N;
  unsigned char* xn = (unsigned char*)(rowsum + 2 * N + 16);

  norm_kernel<<<N / 4, 256, 0, stream>>>(x, xn, rowsum, (float*)d_out);
  sim_kernel<<<NTILES, 256, 0, stream>>>(xn, rowsum, pos);
  loss_kernel<<<N / 256, 256, 0, stream>>>(rowsum, pos, (float*)d_out);
}